// Round 2
// baseline (1128.395 us; speedup 1.0000x reference)
//
#include <hip/hip_runtime.h>

#define N_IN   1000000
#define N_OUT  250000
#define KOFF   8
#define PPAIR  125000
#define NPAIR  1000000          // KOFF * PPAIR
#define C_IN   64
#define C_OUT  128
#define BN_EPS 1e-5f
#define NB     1954             // ceil(N_OUT / 128) row-blocks
#define NBUK   16384            // padded bucket count (used: NB*8 = 15632)
#define PBLK   2048             // partials stride (>= NB)

typedef __attribute__((ext_vector_type(8))) short short8;
typedef __attribute__((ext_vector_type(4))) float floatx4;

// float -> bf16 round-to-nearest-even
__device__ __forceinline__ unsigned short f2bf(float x) {
    unsigned u = __float_as_uint(x);
    unsigned r = u + 0x7FFF + ((u >> 16) & 1);
    return (unsigned short)(r >> 16);
}

// ---------------------------------------------------------------------------
// pack W[k][i][n] fp32 -> Wpack[k][n][i] bf16 (K-major per output column).
// ---------------------------------------------------------------------------
__global__ __launch_bounds__(256) void pack_w(
    const float* __restrict__ W, unsigned short* __restrict__ wp)
{
    int e = blockIdx.x * 256 + threadIdx.x;          // e < 8*64*128 = 65536
    int k = e >> 13;
    int rem = e & 8191;
    int i = rem >> 7;
    int n = rem & 127;
    wp[k * 8192 + n * 64 + i] = f2bf(W[e]);
}

// ---------------------------------------------------------------------------
// Bucket sort by (output-row-block, k): key b = (o>>7)*8 + k.
// ---------------------------------------------------------------------------
__global__ __launch_bounds__(256) void k_count(
    const int* __restrict__ oidx, int* __restrict__ counts)
{
    const int p = blockIdx.x * 256 + threadIdx.x;
    const int k = blockIdx.y;
    if (p < PPAIR) {
        const int o = oidx[k * PPAIR + p];
        atomicAdd(&counts[(o >> 7) * 8 + k], 1);
    }
}

__global__ __launch_bounds__(1024) void k_scanA(
    const int* __restrict__ counts, int* __restrict__ bp, int* __restrict__ bsum)
{
    __shared__ int ls[1024];
    const int tid = threadIdx.x;
    const int i = blockIdx.x * 1024 + tid;           // grid=16 -> covers 16384
    int v = counts[i];
    ls[tid] = v;
    __syncthreads();
    for (int d = 1; d < 1024; d <<= 1) {
        int t = (tid >= d) ? ls[tid - d] : 0;
        __syncthreads();
        ls[tid] += t;
        __syncthreads();
    }
    bp[i] = ls[tid] - v;                             // exclusive, block-local
    if (tid == 1023) bsum[blockIdx.x] = ls[1023];
}

__global__ __launch_bounds__(256) void k_scanB(int* __restrict__ bsum)
{
    __shared__ int ls[256];
    const int tid = threadIdx.x;
    int v = bsum[tid];
    ls[tid] = v;
    __syncthreads();
    for (int d = 1; d < 256; d <<= 1) {
        int t = (tid >= d) ? ls[tid - d] : 0;
        __syncthreads();
        ls[tid] += t;
        __syncthreads();
    }
    bsum[tid] = ls[tid] - v;
}

__global__ __launch_bounds__(1024) void k_scanC(
    int* __restrict__ bp, const int* __restrict__ bsum, int* __restrict__ cursor)
{
    const int i = blockIdx.x * 1024 + threadIdx.x;
    const int r = bp[i] + bsum[blockIdx.x];
    bp[i] = r;
    cursor[i] = r;
}

// perm word packs everything k_conv needs: in-row (20 bits) | out-row-in-block (7 bits)
__global__ __launch_bounds__(256) void k_fill(
    const int* __restrict__ oidx, const int* __restrict__ iidx,
    int* __restrict__ cursor, int* __restrict__ perm)
{
    const int p = blockIdx.x * 256 + threadIdx.x;
    const int k = blockIdx.y;
    if (p < PPAIR) {
        const int o   = oidx[k * PPAIR + p];
        const int iid = iidx[k * PPAIR + p];
        const int slot = atomicAdd(&cursor[(o >> 7) * 8 + k], 1);
        perm[slot] = iid | ((o & 127) << 20);
    }
}

// ---------------------------------------------------------------------------
// Fused gather-GEMM with in-LDS accumulation. One workgroup = 128 output rows
// (64 KB fp32 LDS tile, XOR-bit4 swizzled vs row parity -> <=2-way ds conflicts,
// which are free). Wave w handles k = 2w, 2w+1; within a bucket B=W[k] is
// shared so the 16-pair x 128-ch MFMA tile is unchanged. D scatters into LDS
// via ds_add_f32 (CU-local atomics). Tile is written to `out` once, coalesced;
// BN partials go to a per-block slot with PLAIN stores (no hot global atomics).
// ---------------------------------------------------------------------------
__global__ __launch_bounds__(256) void k_conv(
    const float*          __restrict__ feat,
    const unsigned short* __restrict__ wpack,
    const int*            __restrict__ perm,
    const int*            __restrict__ bp,
    float*                __restrict__ out,
    float*                __restrict__ part)
{
    __shared__ float lacc[16384];                    // [128 rows][128 ch], swizzled
    const int tid  = threadIdx.x;
    const int lane = tid & 63;
    const int wave = tid >> 6;                       // 0..3
    const int quad = lane >> 4;
    const int col  = lane & 15;
    const int blk  = blockIdx.x;

    {   // zero the accumulator tile
        const float4 z = make_float4(0.f, 0.f, 0.f, 0.f);
#pragma unroll
        for (int i = 0; i < 16; ++i)
            ((float4*)lacc)[i * 256 + tid] = z;
    }
    __syncthreads();

#pragma unroll
    for (int kk = 0; kk < 2; ++kk) {
        const int k = wave * 2 + kk;
        const unsigned short* wk = wpack + k * 8192;
        short8 bfrag[2][8];
#pragma unroll
        for (int s = 0; s < 2; ++s)
#pragma unroll
            for (int t = 0; t < 8; ++t)
                bfrag[s][t] = *(const short8*)(wk + (t * 16 + col) * 64 + s * 32 + quad * 8);

        const int b = blk * 8 + k;
        const int start = bp[b], end = bp[b + 1];
        for (int t0 = start; t0 < end; t0 += 16) {
            const int j  = t0 + col;
            const int jc = min(j, end - 1);
            const int e2 = perm[jc];
            const int iid      = e2 & 0xFFFFF;
            const int orow_own = e2 >> 20;           // row within this 128-block

            const float* frow = feat + (long)iid * C_IN;
            short8 afrag[2];
#pragma unroll
            for (int s = 0; s < 2; ++s) {
                const float4 f0 = *(const float4*)(frow + s * 32 + quad * 8);
                const float4 f1 = *(const float4*)(frow + s * 32 + quad * 8 + 4);
                short8 a;
                a[0] = (short)f2bf(f0.x); a[1] = (short)f2bf(f0.y);
                a[2] = (short)f2bf(f0.z); a[3] = (short)f2bf(f0.w);
                a[4] = (short)f2bf(f1.x); a[5] = (short)f2bf(f1.y);
                a[6] = (short)f2bf(f1.z); a[7] = (short)f2bf(f1.w);
                afrag[s] = a;
            }

            floatx4 acc[8];
#pragma unroll
            for (int t = 0; t < 8; ++t) acc[t] = (floatx4){0.f, 0.f, 0.f, 0.f};
#pragma unroll
            for (int s = 0; s < 2; ++s)
#pragma unroll
                for (int t = 0; t < 8; ++t)
                    acc[t] = __builtin_amdgcn_mfma_f32_16x16x32_bf16(
                        afrag[s], bfrag[s][t], acc[t], 0, 0, 0);

            // scatter D into the LDS tile: row m = quad*4+r, ch = t*16+col
#pragma unroll
            for (int r = 0; r < 4; ++r) {
                const int m = quad * 4 + r;
                const int orow = __shfl(orow_own, m);
                if (t0 + m < end) {
                    const int flip = (orow & 1) << 4;
#pragma unroll
                    for (int t = 0; t < 8; ++t)
                        atomicAdd(&lacc[orow * 128 + ((t * 16 + col) ^ flip)], acc[t][r]);
                }
            }
        }
    }
    __syncthreads();

    // per-channel BN partials (rows beyond N_OUT are zero -> harmless)
    const int c = tid & 127;
    const int h = tid >> 7;
    float s = 0.f, q = 0.f;
#pragma unroll 8
    for (int r0 = 0; r0 < 64; ++r0) {
        const int r = h * 64 + r0;
        const float v = lacc[r * 128 + (c ^ ((r & 1) << 4))];
        s += v; q = fmaf(v, v, q);
    }

    // coalesced writeout of the 128x128 fp32 tile
    const long rowbase = (long)blk * 128;
#pragma unroll
    for (int it = 0; it < 16; ++it) {
        const int row = it * 8 + (tid >> 5);
        if (rowbase + row < N_OUT) {
            const int c4 = (tid & 31) * 4;
            const float4 v = *(const float4*)&lacc[row * 128 + (c4 ^ ((row & 1) << 4))];
            *(float4*)&out[(rowbase + row) * 128 + c4] = v;
        }
    }

    // combine the two per-channel halves in LDS, then plain-store partials
    __syncthreads();
    lacc[h * 128 + c]       = s;
    lacc[256 + h * 128 + c] = q;
    __syncthreads();
    if (tid < 128) {
        part[tid * PBLK + blk]         = lacc[tid] + lacc[128 + tid];
        part[(128 + tid) * PBLK + blk] = lacc[256 + tid] + lacc[384 + tid];
    }
}

// reduce the [256][PBLK] partials -> sums[256]  (sum rows 0..127, sumsq 128..255)
__global__ __launch_bounds__(256) void bn_sumreduce(
    const float* __restrict__ part, float* __restrict__ sums)
{
    const int c = blockIdx.x;                        // 0..255
    float s = 0.f;
    for (int b = threadIdx.x; b < NB; b += 256)
        s += part[c * PBLK + b];
    __shared__ float ls[256];
    ls[threadIdx.x] = s;
    __syncthreads();
    for (int d = 128; d > 0; d >>= 1) {
        if (threadIdx.x < d) ls[threadIdx.x] += ls[threadIdx.x + d];
        __syncthreads();
    }
    if (threadIdx.x == 0) sums[c] = ls[0];
}

__global__ __launch_bounds__(128) void bn_finalize(
    const float* __restrict__ sums,
    const float* __restrict__ gamma,
    const float* __restrict__ beta,
    float*       __restrict__ ss)
{
    const int c = threadIdx.x;
    const float inv_n = 1.0f / (float)N_OUT;
    const float mean  = sums[c] * inv_n;
    const float var   = sums[128 + c] * inv_n - mean * mean;
    const float sc    = gamma[c] * rsqrtf(var + BN_EPS);
    ss[c]       = sc;
    ss[128 + c] = fmaf(-mean, sc, beta[c]);
}

// BN apply + ReLU, fp32 in place
__global__ __launch_bounds__(256) void bn_apply_f(
    float* __restrict__ out, const float* __restrict__ ss)
{
    const long j = (long)blockIdx.x * 256 + threadIdx.x;
    const int c = ((int)j & 31) * 4;
    float4 v = ((const float4*)out)[j];
    v.x = fmaxf(0.f, fmaf(v.x, ss[c + 0], ss[128 + c + 0]));
    v.y = fmaxf(0.f, fmaf(v.y, ss[c + 1], ss[128 + c + 1]));
    v.z = fmaxf(0.f, fmaf(v.z, ss[c + 2], ss[128 + c + 2]));
    v.w = fmaxf(0.f, fmaf(v.w, ss[c + 3], ss[128 + c + 3]));
    ((float4*)out)[j] = v;
}

// ---------------------------------------------------------------------------
// Small-workspace fallback: fp32 atomic scatter (previous MODE 0) + bn_stats_f
// ---------------------------------------------------------------------------
__global__ __launch_bounds__(256) void scatter_fp32(
    const float*          __restrict__ feat,
    const unsigned short* __restrict__ wpack,
    const int*            __restrict__ in_idx,
    const int*            __restrict__ out_idx,
    float*                __restrict__ facc)
{
    const int lane = threadIdx.x & 63;
    const int wave = threadIdx.x >> 6;
    const int quad = lane >> 4;
    const int col  = lane & 15;
    const int k    = blockIdx.y;
    const int base = blockIdx.x * 64 + wave * 16;

    const int gp_a = base + col;
    const int iid  = (gp_a < PPAIR) ? in_idx[k * PPAIR + gp_a] : 0;
    const float* frow = feat + (long)iid * C_IN;

    short8 afrag[2];
#pragma unroll
    for (int s = 0; s < 2; ++s) {
        const float4 f0 = *(const float4*)(frow + s * 32 + quad * 8);
        const float4 f1 = *(const float4*)(frow + s * 32 + quad * 8 + 4);
        short8 a;
        a[0] = (short)f2bf(f0.x); a[1] = (short)f2bf(f0.y);
        a[2] = (short)f2bf(f0.z); a[3] = (short)f2bf(f0.w);
        a[4] = (short)f2bf(f1.x); a[5] = (short)f2bf(f1.y);
        a[6] = (short)f2bf(f1.z); a[7] = (short)f2bf(f1.w);
        afrag[s] = a;
    }

    const unsigned short* wk = wpack + k * 8192;
    short8 bfrag[2][8];
#pragma unroll
    for (int s = 0; s < 2; ++s)
#pragma unroll
        for (int t = 0; t < 8; ++t)
            bfrag[s][t] = *(const short8*)(wk + (t * 16 + col) * 64 + s * 32 + quad * 8);

    floatx4 acc[8];
#pragma unroll
    for (int t = 0; t < 8; ++t) acc[t] = (floatx4){0.f, 0.f, 0.f, 0.f};
#pragma unroll
    for (int s = 0; s < 2; ++s)
#pragma unroll
        for (int t = 0; t < 8; ++t)
            acc[t] = __builtin_amdgcn_mfma_f32_16x16x32_bf16(
                afrag[s], bfrag[s][t], acc[t], 0, 0, 0);

    int oid[4];
#pragma unroll
    for (int r = 0; r < 4; ++r) {
        const int gp = base + quad * 4 + r;
        oid[r] = (gp < PPAIR) ? out_idx[k * PPAIR + gp] : -1;
    }
#pragma unroll
    for (int t = 0; t < 8; ++t)
#pragma unroll
        for (int r = 0; r < 4; ++r)
            if (oid[r] >= 0)
                atomicAdd(facc + (long)oid[r] * C_OUT + t * 16 + col, acc[t][r]);
}

__global__ __launch_bounds__(512) void bn_stats_f(
    const float* __restrict__ out, float* __restrict__ sums)
{
    const int c = threadIdx.x & 127;
    const int g = threadIdx.x >> 7;
    float s = 0.f, q = 0.f;
    for (int r = blockIdx.x * 4 + g; r < N_OUT; r += gridDim.x * 4) {
        const float x = out[(long)r * C_OUT + c];
        s += x; q = fmaf(x, x, q);
    }
    __shared__ float ls[512], lq[512];
    ls[threadIdx.x] = s; lq[threadIdx.x] = q;
    __syncthreads();
    if (g == 0) {
        atomicAdd(&sums[c],       ls[c] + ls[128 + c] + ls[256 + c] + ls[384 + c]);
        atomicAdd(&sums[128 + c], lq[c] + lq[128 + c] + lq[256 + c] + lq[384 + c]);
    }
}

// ---------------------------------------------------------------------------
extern "C" void kernel_launch(void* const* d_in, const int* in_sizes, int n_in,
                              void* d_out, int out_size, void* d_ws, size_t ws_size,
                              hipStream_t stream)
{
    const float* feat    = (const float*)d_in[0];
    const float* weight  = (const float*)d_in[1];
    const float* gamma   = (const float*)d_in[2];
    const float* beta    = (const float*)d_in[3];
    const int*   in_idx  = (const int*)  d_in[4];
    const int*   out_idx = (const int*)  d_in[5];
    float* out = (float*)d_out;
    char* wsb = (char*)d_ws;

    // workspace layout (bucketed path): ~6.3 MB
    const size_t OFF_PERM = 0;                       // int[NPAIR]        4 MB
    const size_t OFF_CNT  = 4194304;                 // int[NBUK]         64 KB
    const size_t OFF_BP   = OFF_CNT  + 65536;        // int[NBUK+1]       64+ KB
    const size_t OFF_CUR  = OFF_BP   + 65664;        // int[NBUK]
    const size_t OFF_BSUM = OFF_CUR  + 65536;        // int[256]
    const size_t OFF_PART = OFF_BSUM + 1024;         // float[256*PBLK]   2 MB
    const size_t OFF_SUM  = OFF_PART + (size_t)256 * PBLK * 4;
    const size_t OFF_SS   = OFF_SUM  + 1024;
    const size_t OFF_WP   = OFF_SS   + 1024;
    const size_t NEED     = OFF_WP   + 131072;

    const int nblk_apply = (int)((long)N_OUT * C_OUT / 4 / 256);   // 31250

    if (ws_size >= NEED) {
        int*   perm   = (int*)(wsb + OFF_PERM);
        int*   counts = (int*)(wsb + OFF_CNT);
        int*   bp     = (int*)(wsb + OFF_BP);
        int*   cursor = (int*)(wsb + OFF_CUR);
        int*   bsum   = (int*)(wsb + OFF_BSUM);
        float* part   = (float*)(wsb + OFF_PART);
        float* sums   = (float*)(wsb + OFF_SUM);
        float* ss     = (float*)(wsb + OFF_SS);
        unsigned short* wpack = (unsigned short*)(wsb + OFF_WP);

        hipMemsetAsync(counts, 0, NBUK * sizeof(int), stream);
        hipMemsetAsync(bsum, 0, 1024, stream);

        pack_w<<<256, 256, 0, stream>>>(weight, wpack);
        dim3 gp2((PPAIR + 255) / 256, KOFF);
        k_count<<<gp2, 256, 0, stream>>>(out_idx, counts);
        k_scanA<<<16, 1024, 0, stream>>>(counts, bp, bsum);
        k_scanB<<<1, 256, 0, stream>>>(bsum);
        k_scanC<<<16, 1024, 0, stream>>>(bp, bsum, cursor);
        k_fill<<<gp2, 256, 0, stream>>>(out_idx, in_idx, cursor, perm);
        k_conv<<<NB, 256, 0, stream>>>(feat, wpack, perm, bp, out, part);
        bn_sumreduce<<<256, 256, 0, stream>>>(part, sums);
        bn_finalize<<<1, 128, 0, stream>>>(sums, gamma, beta, ss);
        bn_apply_f<<<nblk_apply, 256, 0, stream>>>(out, ss);
    } else {
        // minimal-ws fallback: fp32 atomic scatter
        float* sums = (float*)wsb;
        float* ss   = (float*)(wsb + 1024);
        unsigned short* wpack = (unsigned short*)(wsb + 2048);

        hipMemsetAsync(out, 0, (size_t)N_OUT * C_OUT * sizeof(float), stream);
        hipMemsetAsync(sums, 0, 256 * sizeof(float), stream);
        pack_w<<<256, 256, 0, stream>>>(weight, wpack);
        dim3 g1((PPAIR + 63) / 64, KOFF);
        scatter_fp32<<<g1, 256, 0, stream>>>(feat, wpack, in_idx, out_idx, out);
        bn_stats_f<<<256, 512, 0, stream>>>(out, sums);
        bn_finalize<<<1, 128, 0, stream>>>(sums, gamma, beta, ss);
        bn_apply_f<<<nblk_apply, 256, 0, stream>>>(out, ss);
    }
}